// Round 1
// baseline (633.592 us; speedup 1.0000x reference)
//
#include <hip/hip_runtime.h>
#include <hip/hip_fp16.h>
#include <math.h>

#define IN0    128
#define HEADS  4
#define CDIM   64
#define HC     256
#define SLOPE  0.2f
#define NPAD   50176   // 392*128, row padding
#define BK     32      // k-chunk (halves) = 64 B

typedef __attribute__((ext_vector_type(8))) _Float16 f16x8;
typedef __attribute__((ext_vector_type(4))) float f32x4;

__device__ __forceinline__ float h2f(ushort u) {
    __half h = *(const __half*)&u;
    return __half2float(h);
}
__device__ __forceinline__ ushort f2h(float f) {
    __half h = __float2half_rn(f);
    return *(ushort*)&h;
}

// ---------------- fused prep: degree + xconv(fp16,chunked) + wconv(fp16,chunked) x3 ----------------

__device__ __forceinline__ void wconv_body(const float* __restrict__ W,
                                           ushort* __restrict__ Wc, int K, int b) {
    int tid = b * 256 + threadIdx.x;     // K*256 threads
    int n = tid & 255;                   // output col (coalesced read)
    int k = tid >> 8;
    if (k >= K) return;
    Wc[(size_t)(k >> 5) * (HC * BK) + n * BK + (k & 31)] = f2h(W[(size_t)k * HC + n]);
}

__global__ __launch_bounds__(256) void k_prep(
        const int* __restrict__ dst_rand, int E_rand, int* __restrict__ deg,
        const float* __restrict__ x0, ushort* __restrict__ Xc, int totalx,
        const float* __restrict__ W0, ushort* __restrict__ Wc0,
        const float* __restrict__ W1, ushort* __restrict__ Wc1,
        const float* __restrict__ W2, ushort* __restrict__ Wc2,
        int B0, int B1) {
    int b = blockIdx.x;
    if (b < B0) {
        int i = b * 256 + threadIdx.x;
        if (i < E_rand) atomicAdd(&deg[dst_rand[i]], 1);
        return;
    }
    b -= B0;
    if (b < B1) {                        // xconv: x0 [N][128] -> Xc [4][NPAD][32]
        int i = b * 256 + threadIdx.x;
        if (i < totalx) {
            int n = i >> 7, k = i & 127;
            Xc[(size_t)(k >> 5) * (NPAD * BK) + n * BK + (k & 31)] = f2h(x0[i]);
        }
        return;
    }
    b -= B1;
    if (b < 128) { wconv_body(W0, Wc0, 128, b); return; }
    b -= 128;
    if (b < 256) { wconv_body(W1, Wc1, 256, b); return; }
    b -= 256;
    wconv_body(W2, Wc2, 256, b);
}

// ---------------- single-kernel scan (prefix-of-prefixes brute force) ----------------

__global__ __launch_bounds__(1024) void k_scan(const int* __restrict__ deg, int Nn,
                                               int* __restrict__ rowptr,
                                               int* __restrict__ cur) {
    __shared__ int smem[1024];
    int tid = threadIdx.x;
    int pre = 0;
    int limit = blockIdx.x * 1024;
    for (int i = tid; i < limit; i += 1024) pre += deg[i];
    smem[tid] = pre;
    __syncthreads();
    #pragma unroll
    for (int d = 512; d >= 1; d >>= 1) {
        if (tid < d) smem[tid] += smem[tid + d];
        __syncthreads();
    }
    int s_off = smem[0];
    __syncthreads();
    int i = blockIdx.x * 1024 + tid;
    int v = (i < Nn) ? deg[i] : 0;
    smem[tid] = v;
    __syncthreads();
    #pragma unroll
    for (int d = 1; d < 1024; d <<= 1) {
        int t = 0;
        if (tid >= d) t = smem[tid - d];
        __syncthreads();
        smem[tid] += t;
        __syncthreads();
    }
    if (i < Nn) {
        int e = s_off + smem[tid] - v;
        rowptr[i] = e;
        cur[i] = e;
    }
    if (blockIdx.x == gridDim.x - 1 && tid == 1023) rowptr[Nn] = s_off + smem[1023];
}

__global__ void k_scatter(const int* __restrict__ src, const int* __restrict__ dst, int E_rand,
                          int* __restrict__ cur, int* __restrict__ csr_src) {
    int i = blockIdx.x * blockDim.x + threadIdx.x;
    if (i < E_rand) {
        int d = dst[i];
        int p = atomicAdd(&cur[d], 1);
        csr_src[p] = src[i];
    }
}

// ---------------- fused GEMM + attention scores (fp16 MFMA, no LDS, chunked operands) ----------------
// Grid: 784 linear = 49 groups x 16; siblings (same rows, both col-halves) placed 8 apart
// so they land on the same XCD (id%8 round-robin) and share X rows in L2.
// H output is stored CHUNKED [HC/32][NPAD][32] so the aggregate can slice it per-XCD.
// a_src/a_dst are stored as per-head planes [HEADS][M] for per-XCD L2 residency.

template<int K>
__global__ __launch_bounds__(256) void k_gemm_att(const ushort* __restrict__ Xc,
                                                  const ushort* __restrict__ Wc,
                                                  const float* __restrict__ attS,
                                                  const float* __restrict__ attD,
                                                  ushort* __restrict__ H16out,
                                                  float* __restrict__ a_src_v,
                                                  float* __restrict__ a_dst_v,
                                                  int M) {
    int id    = blockIdx.x;
    int group = id >> 4;
    int sub   = id & 15;
    int row0  = (group * 8 + (sub & 7)) * 128;
    int colb  = sub >> 3;
    int col0  = colb * 128;

    int t    = threadIdx.x;
    int wave = t >> 6, lane = t & 63;
    int wm = wave & 1, wn = wave >> 1;
    int quad = lane >> 4, l16 = lane & 15;

    f32x4 acc[4][4];
    #pragma unroll
    for (int i = 0; i < 4; i++)
        #pragma unroll
        for (int j = 0; j < 4; j++) acc[i][j] = (f32x4){0.f, 0.f, 0.f, 0.f};

    constexpr int NK = K / BK;
    #pragma unroll
    for (int kc = 0; kc < NK; kc++) {
        f16x8 a[4], b[4];
        #pragma unroll
        for (int mt = 0; mt < 4; mt++) {
            size_t ga = (size_t)kc * (NPAD * BK)
                      + (size_t)(row0 + wm * 64 + mt * 16 + l16) * BK + quad * 8;
            a[mt] = *(const f16x8*)&Xc[ga];
        }
        #pragma unroll
        for (int nt = 0; nt < 4; nt++) {
            size_t gb = (size_t)kc * (HC * BK)
                      + (size_t)(col0 + wn * 64 + nt * 16 + l16) * BK + quad * 8;
            b[nt] = *(const f16x8*)&Wc[gb];
        }
        #pragma unroll
        for (int mt = 0; mt < 4; mt++)
            #pragma unroll
            for (int nt = 0; nt < 4; nt++)
                acc[mt][nt] = __builtin_amdgcn_mfma_f32_16x16x32_f16(a[mt], b[nt], acc[mt][nt], 0, 0, 0);
    }

    // epilogue 1: store H as fp16 CHUNKED (C/D layout col=lane&15, row=quad*4+reg)
    #pragma unroll
    for (int mt = 0; mt < 4; mt++) {
        #pragma unroll
        for (int r = 0; r < 4; r++) {
            int row = row0 + wm*64 + mt*16 + quad*4 + r;
            if (row >= M) continue;
            #pragma unroll
            for (int nt = 0; nt < 4; nt++) {
                int col = col0 + wn*64 + nt*16 + l16;
                size_t idx = (size_t)(col >> 5) * (NPAD * 32) + (size_t)row * 32 + (col & 31);
                H16out[idx] = f2h(acc[mt][nt][r]);
            }
        }
    }

    // epilogue 2: att score dots; this wave's cols = head (2*colb + wn).
    int headw = colb * 2 + wn;
    float sS[4], sD[4];
    #pragma unroll
    for (int nt = 0; nt < 4; nt++) {
        sS[nt] = attS[headw * CDIM + nt*16 + l16];
        sD[nt] = attD[headw * CDIM + nt*16 + l16];
    }
    #pragma unroll
    for (int mt = 0; mt < 4; mt++) {
        #pragma unroll
        for (int r = 0; r < 4; r++) {
            float ps = 0.f, pd = 0.f;
            #pragma unroll
            for (int nt = 0; nt < 4; nt++) {
                float av = acc[mt][nt][r];
                ps += av * sS[nt];
                pd += av * sD[nt];
            }
            #pragma unroll
            for (int d = 1; d <= 8; d <<= 1) {
                ps += __shfl_xor(ps, d);
                pd += __shfl_xor(pd, d);
            }
            int row = row0 + wm*64 + mt*16 + quad*4 + r;
            if (l16 == 0 && row < M) {
                a_src_v[(size_t)headw * M + row] = ps;
                a_dst_v[(size_t)headw * M + row] = pd;
            }
        }
    }
}

// ---------------- aggregation: XCD-sliced channel gather ----------------
// 1 wave = one (node, 32-ch slice). slice = blockIdx%8 -> lands on XCD slice
// (round-robin dispatch), so each XCD's L2 holds only its 3.2 MB slice of H
// plus its head's 200 KB score plane -> gathers become L2 hits.
// Lanes: 8 edge-slots (es=lane>>3) x 8 channel-quads (c8=lane&7);
// one ushort4 gather instruction covers 8 edges x 64 B.

__global__ __launch_bounds__(256) void k_aggregate(
        const ushort* __restrict__ Hc,      // chunked fp16 [8][NPAD][32]
        const float* __restrict__ a_srcP,   // [HEADS][Nn]
        const float* __restrict__ a_dstP,   // [HEADS][Nn]
        const int* __restrict__ rowptr, const int* __restrict__ csr_src,
        const float* __restrict__ bias,
        float* __restrict__ out_f32,        // nullable
        ushort* __restrict__ out_h16c,      // nullable (fp16, CHUNKED)
        int Nn) {
    int lane  = threadIdx.x & 63;
    int slice = blockIdx.x & 7;             // == XCD under round-robin dispatch
    int n = (blockIdx.x >> 3) * 4 + (threadIdx.x >> 6);
    if (n >= Nn) return;
    int h  = slice >> 1;
    int es = lane >> 3;                     // edge sub-slot 0..7
    int c8 = lane & 7;                      // channel quad: ch = slice*32 + c8*4

    const char* Hs = (const char*)(Hc + (size_t)slice * (NPAD * 32));
    const float* aS = a_srcP + (size_t)h * Nn;

    int beg = rowptr[n], end = rowptr[n + 1];
    int deg = end - beg;
    float adst = a_dstP[(size_t)h * Nn + n];
    float e_self = aS[n] + adst;
    e_self = (e_self > 0.f) ? e_self : SLOPE * e_self;
    float ex_self = __expf(e_self);

    float ssum = 0.f;
    float4 acc = make_float4(0.f, 0.f, 0.f, 0.f);

    for (int base = 0; base < deg; base += 64) {
        int cnt = min(64, deg - base);
        int s_l = 0; float ex_l = 0.f;
        if (lane < cnt) {
            s_l = csr_src[beg + base + lane];
            float e = aS[s_l] + adst;
            e = (e > 0.f) ? e : SLOPE * e;
            ex_l = __expf(e);
            ssum += ex_l;
        }
        int off_l = s_l * 64;               // byte offset of source row in slice
        int cnt8 = (cnt + 7) & ~7;          // OOB slots: ex=0, off=0 (harmless hot load)
        for (int j = 0; j < cnt8; j += 8) {
            float a = __shfl(ex_l,  j + es);
            int   o = __shfl(off_l, j + es);
            ushort4 u = *(const ushort4*)(Hs + o + c8 * 8);
            acc.x += a * h2f(u.x);
            acc.y += a * h2f(u.y);
            acc.z += a * h2f(u.z);
            acc.w += a * h2f(u.w);
        }
    }
    // softmax denom: each lane held distinct edge slots -> full-wave sum
    #pragma unroll
    for (int d = 1; d < 64; d <<= 1) ssum += __shfl_xor(ssum, d);
    ssum += ex_self;
    // acc: reduce across edge sub-slots (lane bits 3..5)
    #pragma unroll
    for (int d = 8; d <= 32; d <<= 1) {
        acc.x += __shfl_xor(acc.x, d);
        acc.y += __shfl_xor(acc.y, d);
        acc.z += __shfl_xor(acc.z, d);
        acc.w += __shfl_xor(acc.w, d);
    }
    float rden = 1.f / (ssum + 1e-16f);
    ushort4 us = *(const ushort4*)(Hs + (size_t)n * 64 + c8 * 8);
    int ch = slice * 32 + c8 * 4;
    float4 b = *(const float4*)&bias[ch];
    float4 o4;
    o4.x = fmaxf((acc.x + ex_self * h2f(us.x)) * rden + b.x, 0.f);
    o4.y = fmaxf((acc.y + ex_self * h2f(us.y)) * rden + b.y, 0.f);
    o4.z = fmaxf((acc.z + ex_self * h2f(us.z)) * rden + b.z, 0.f);
    o4.w = fmaxf((acc.w + ex_self * h2f(us.w)) * rden + b.w, 0.f);
    if (es == 0) {                          // lanes 0..7 write 8 x 16B = 128B contiguous
        if (out_f32) {
            *(float4*)&out_f32[(size_t)n * HC + ch] = o4;
        }
        if (out_h16c) {
            size_t idx = (size_t)slice * (NPAD * 32) + (size_t)n * 32 + c8 * 4;
            *(ushort4*)&out_h16c[idx] = make_ushort4(f2h(o4.x), f2h(o4.y), f2h(o4.z), f2h(o4.w));
        }
    }
}

// ---------------- launch ----------------

extern "C" void kernel_launch(void* const* d_in, const int* in_sizes, int n_in,
                              void* d_out, int out_size, void* d_ws, size_t ws_size,
                              hipStream_t stream) {
    const float* x0   = (const float*)d_in[0];
    const int*   eidx = (const int*)d_in[1];
    int Nn = in_sizes[0] / IN0;     // 50000
    int E  = in_sizes[1] / 2;       // 850000
    int E_rand = E - Nn;            // 800000 random edges; self-loops inline
    const int* srcp = eidx;
    const int* dstp = eidx + E;

    const float* Wl[3]    = {(const float*)d_in[2],  (const float*)d_in[6],  (const float*)d_in[10]};
    const float* attS[3]  = {(const float*)d_in[3],  (const float*)d_in[7],  (const float*)d_in[11]};
    const float* attD[3]  = {(const float*)d_in[4],  (const float*)d_in[8],  (const float*)d_in[12]};
    const float* biasl[3] = {(const float*)d_in[5],  (const float*)d_in[9],  (const float*)d_in[13]};
    int Kdims[3] = {IN0, HC, HC};

    // workspace carve
    char* p = (char*)d_ws;
    ushort* h16    = (ushort*)p; p += (size_t)NPAD * HC * sizeof(ushort);   // chunked [8][NPAD][32]
    ushort* Xc     = (ushort*)p; p += (size_t)NPAD * HC * sizeof(ushort);   // chunked
    float*  a_src_v= (float*)p;  p += (size_t)Nn * HEADS * sizeof(float);   // [H][Nn] planes
    float*  a_dst_v= (float*)p;  p += (size_t)Nn * HEADS * sizeof(float);   // [H][Nn] planes
    int*    rowptr = (int*)p;    p += (size_t)(Nn + 1) * sizeof(int);
    int*    deg    = (int*)p;    p += (size_t)Nn * sizeof(int);
    int*    cur    = (int*)p;    p += (size_t)Nn * sizeof(int);
    int*    csr_src= (int*)p;    p += (size_t)E_rand * sizeof(int);
    ushort* Wc[3];
    for (int l = 0; l < 3; l++) {
        Wc[l] = (ushort*)p; p += (size_t)HC * Kdims[l] * sizeof(ushort);
    }

    int NB = (Nn + 1023) / 1024;
    int B0 = (E_rand + 255) / 256;
    int B1 = (Nn * IN0 + 255) / 256;
    int Bprep = B0 + B1 + 128 + 256 + 256;

    hipMemsetAsync(deg, 0, (size_t)Nn * sizeof(int), stream);
    k_prep<<<Bprep, 256, 0, stream>>>(dstp, E_rand, deg,
                                      x0, Xc, Nn * IN0,
                                      Wl[0], Wc[0], Wl[1], Wc[1], Wl[2], Wc[2],
                                      B0, B1);
    k_scan<<<NB, 1024, 0, stream>>>(deg, Nn, rowptr, cur);
    k_scatter<<<(E_rand + 255) / 256, 256, 0, stream>>>(srcp, dstp, E_rand, cur, csr_src);

    dim3 g(784);                 // 49 groups x (8 row-blocks x 2 col-blocks), XCD-swizzled
    dim3 ga(8 * ((Nn + 3) / 4)); // (node-group x slice); slice = bid%8 -> XCD affinity
    for (int l = 0; l < 3; l++) {
        if (l == 0)
            k_gemm_att<128><<<g, 256, 0, stream>>>(Xc, Wc[l], attS[l], attD[l],
                                                   h16, a_src_v, a_dst_v, Nn);
        else
            k_gemm_att<256><<<g, 256, 0, stream>>>(Xc, Wc[l], attS[l], attD[l],
                                                   h16, a_src_v, a_dst_v, Nn);
        if (l < 2) {
            k_aggregate<<<ga, 256, 0, stream>>>(h16, a_src_v, a_dst_v, rowptr, csr_src,
                                                biasl[l], nullptr, Xc, Nn);
        } else {
            k_aggregate<<<ga, 256, 0, stream>>>(h16, a_src_v, a_dst_v, rowptr, csr_src,
                                                biasl[l], (float*)d_out, nullptr, Nn);
        }
    }
}

// Round 2
// 517.079 us; speedup vs baseline: 1.2253x; 1.2253x over previous
//
#include <hip/hip_runtime.h>
#include <hip/hip_fp16.h>
#include <math.h>

#define IN0    128
#define HEADS  4
#define CDIM   64
#define HC     256
#define SLOPE  0.2f
#define NPAD   50176   // 392*128, row padding
#define BK     32      // k-chunk (halves) = 64 B

typedef __attribute__((ext_vector_type(8))) _Float16 f16x8;
typedef __attribute__((ext_vector_type(4))) float f32x4;

__device__ __forceinline__ float h2f(ushort u) {
    __half h = *(const __half*)&u;
    return __half2float(h);
}
__device__ __forceinline__ ushort f2h(float f) {
    __half h = __float2half_rn(f);
    return *(ushort*)&h;
}

// ---------------- fused prep: degree + xconv(fp16,chunked) + wconv(fp16,chunked) x3 ----------------

__device__ __forceinline__ void wconv_body(const float* __restrict__ W,
                                           ushort* __restrict__ Wc, int K, int b) {
    int tid = b * 256 + threadIdx.x;     // K*256 threads
    int n = tid & 255;                   // output col (coalesced read)
    int k = tid >> 8;
    if (k >= K) return;
    Wc[(size_t)(k >> 5) * (HC * BK) + n * BK + (k & 31)] = f2h(W[(size_t)k * HC + n]);
}

__global__ __launch_bounds__(256) void k_prep(
        const int* __restrict__ dst_rand, int E_rand, int* __restrict__ deg,
        const float* __restrict__ x0, ushort* __restrict__ Xc, int totalx,
        const float* __restrict__ W0, ushort* __restrict__ Wc0,
        const float* __restrict__ W1, ushort* __restrict__ Wc1,
        const float* __restrict__ W2, ushort* __restrict__ Wc2,
        int B0, int B1) {
    int b = blockIdx.x;
    if (b < B0) {
        int i = b * 256 + threadIdx.x;
        if (i < E_rand) atomicAdd(&deg[dst_rand[i]], 1);
        return;
    }
    b -= B0;
    if (b < B1) {                        // xconv: x0 [N][128] -> Xc [4][NPAD][32]
        int i = b * 256 + threadIdx.x;
        if (i < totalx) {
            int n = i >> 7, k = i & 127;
            Xc[(size_t)(k >> 5) * (NPAD * BK) + n * BK + (k & 31)] = f2h(x0[i]);
        }
        return;
    }
    b -= B1;
    if (b < 128) { wconv_body(W0, Wc0, 128, b); return; }
    b -= 128;
    if (b < 256) { wconv_body(W1, Wc1, 256, b); return; }
    b -= 256;
    wconv_body(W2, Wc2, 256, b);
}

// ---------------- single-kernel scan (prefix-of-prefixes brute force) ----------------

__global__ __launch_bounds__(1024) void k_scan(const int* __restrict__ deg, int Nn,
                                               int* __restrict__ rowptr,
                                               int* __restrict__ cur) {
    __shared__ int smem[1024];
    int tid = threadIdx.x;
    int pre = 0;
    int limit = blockIdx.x * 1024;
    for (int i = tid; i < limit; i += 1024) pre += deg[i];
    smem[tid] = pre;
    __syncthreads();
    #pragma unroll
    for (int d = 512; d >= 1; d >>= 1) {
        if (tid < d) smem[tid] += smem[tid + d];
        __syncthreads();
    }
    int s_off = smem[0];
    __syncthreads();
    int i = blockIdx.x * 1024 + tid;
    int v = (i < Nn) ? deg[i] : 0;
    smem[tid] = v;
    __syncthreads();
    #pragma unroll
    for (int d = 1; d < 1024; d <<= 1) {
        int t = 0;
        if (tid >= d) t = smem[tid - d];
        __syncthreads();
        smem[tid] += t;
        __syncthreads();
    }
    if (i < Nn) {
        int e = s_off + smem[tid] - v;
        rowptr[i] = e;
        cur[i] = e;
    }
    if (blockIdx.x == gridDim.x - 1 && tid == 1023) rowptr[Nn] = s_off + smem[1023];
}

__global__ void k_scatter(const int* __restrict__ src, const int* __restrict__ dst, int E_rand,
                          int* __restrict__ cur, int* __restrict__ csr_src) {
    int i = blockIdx.x * blockDim.x + threadIdx.x;
    if (i < E_rand) {
        int d = dst[i];
        int p = atomicAdd(&cur[d], 1);
        csr_src[p] = src[i];
    }
}

// ---------------- fused GEMM + attention scores (fp16 MFMA, no LDS, chunked operands) ----------------
// Grid: 784 linear = 49 groups x 16; siblings (same rows, both col-halves) placed 8 apart
// so they land on the same XCD (id%8 round-robin) and share X rows in L2.
// H output is stored CHUNKED [HC/32][NPAD][32] so the aggregate can slice it per-XCD.
// a_src/a_dst are stored as per-head planes [HEADS][M] for per-XCD L2 residency.

template<int K>
__global__ __launch_bounds__(256) void k_gemm_att(const ushort* __restrict__ Xc,
                                                  const ushort* __restrict__ Wc,
                                                  const float* __restrict__ attS,
                                                  const float* __restrict__ attD,
                                                  ushort* __restrict__ H16out,
                                                  float* __restrict__ a_src_v,
                                                  float* __restrict__ a_dst_v,
                                                  int M) {
    int id    = blockIdx.x;
    int group = id >> 4;
    int sub   = id & 15;
    int row0  = (group * 8 + (sub & 7)) * 128;
    int colb  = sub >> 3;
    int col0  = colb * 128;

    int t    = threadIdx.x;
    int wave = t >> 6, lane = t & 63;
    int wm = wave & 1, wn = wave >> 1;
    int quad = lane >> 4, l16 = lane & 15;

    f32x4 acc[4][4];
    #pragma unroll
    for (int i = 0; i < 4; i++)
        #pragma unroll
        for (int j = 0; j < 4; j++) acc[i][j] = (f32x4){0.f, 0.f, 0.f, 0.f};

    constexpr int NK = K / BK;
    #pragma unroll
    for (int kc = 0; kc < NK; kc++) {
        f16x8 a[4], b[4];
        #pragma unroll
        for (int mt = 0; mt < 4; mt++) {
            size_t ga = (size_t)kc * (NPAD * BK)
                      + (size_t)(row0 + wm * 64 + mt * 16 + l16) * BK + quad * 8;
            a[mt] = *(const f16x8*)&Xc[ga];
        }
        #pragma unroll
        for (int nt = 0; nt < 4; nt++) {
            size_t gb = (size_t)kc * (HC * BK)
                      + (size_t)(col0 + wn * 64 + nt * 16 + l16) * BK + quad * 8;
            b[nt] = *(const f16x8*)&Wc[gb];
        }
        #pragma unroll
        for (int mt = 0; mt < 4; mt++)
            #pragma unroll
            for (int nt = 0; nt < 4; nt++)
                acc[mt][nt] = __builtin_amdgcn_mfma_f32_16x16x32_f16(a[mt], b[nt], acc[mt][nt], 0, 0, 0);
    }

    // epilogue 1: store H as fp16 CHUNKED (C/D layout col=lane&15, row=quad*4+reg)
    #pragma unroll
    for (int mt = 0; mt < 4; mt++) {
        #pragma unroll
        for (int r = 0; r < 4; r++) {
            int row = row0 + wm*64 + mt*16 + quad*4 + r;
            if (row >= M) continue;
            #pragma unroll
            for (int nt = 0; nt < 4; nt++) {
                int col = col0 + wn*64 + nt*16 + l16;
                size_t idx = (size_t)(col >> 5) * (NPAD * 32) + (size_t)row * 32 + (col & 31);
                H16out[idx] = f2h(acc[mt][nt][r]);
            }
        }
    }

    // epilogue 2: att score dots; this wave's cols = head (2*colb + wn).
    int headw = colb * 2 + wn;
    float sS[4], sD[4];
    #pragma unroll
    for (int nt = 0; nt < 4; nt++) {
        sS[nt] = attS[headw * CDIM + nt*16 + l16];
        sD[nt] = attD[headw * CDIM + nt*16 + l16];
    }
    #pragma unroll
    for (int mt = 0; mt < 4; mt++) {
        #pragma unroll
        for (int r = 0; r < 4; r++) {
            float ps = 0.f, pd = 0.f;
            #pragma unroll
            for (int nt = 0; nt < 4; nt++) {
                float av = acc[mt][nt][r];
                ps += av * sS[nt];
                pd += av * sD[nt];
            }
            #pragma unroll
            for (int d = 1; d <= 8; d <<= 1) {
                ps += __shfl_xor(ps, d);
                pd += __shfl_xor(pd, d);
            }
            int row = row0 + wm*64 + mt*16 + quad*4 + r;
            if (l16 == 0 && row < M) {
                a_src_v[(size_t)headw * M + row] = ps;
                a_dst_v[(size_t)headw * M + row] = pd;
            }
        }
    }
}

// ---------------- aggregation: XCD-sliced, 8 nodes/wave, lane-private accumulators ----------------
// slice = blockIdx%8 -> XCD affinity (round-robin dispatch): each XCD's L2 holds
// its 3.2 MB H-slice + 200 KB score plane -> H gathers are L2 hits (proven r1:
// FETCH 210->45 MB). r1's regression was decomposition overhead (400k waves x
// metadata phase + 18-shfl reductions). Fix: lane = node_sub(3b) x ch-quad(3b);
// each lane exclusively owns (node, 4ch) -> ssum/acc fully lane-private,
// ZERO shuffles in loop, ZERO final reductions; 50k waves.
// The 8 nodes of a wave are consecutive -> their csr ranges form one contiguous
// ~512B window (L1-resident across the edge loop).

__global__ __launch_bounds__(256) void k_aggregate(
        const ushort* __restrict__ Hc,      // chunked fp16 [8][NPAD][32]
        const float* __restrict__ a_srcP,   // [HEADS][Nn]
        const float* __restrict__ a_dstP,   // [HEADS][Nn]
        const int* __restrict__ rowptr, const int* __restrict__ csr_src,
        const float* __restrict__ bias,
        float* __restrict__ out_f32,        // nullable
        ushort* __restrict__ out_h16c,      // nullable (fp16, CHUNKED)
        int Nn) {
    int lane  = threadIdx.x & 63;
    int wave  = threadIdx.x >> 6;
    int slice = blockIdx.x & 7;             // == XCD under round-robin dispatch
    int c8    = lane & 7;                   // channel quad: ch = slice*32 + c8*4
    int nsub  = lane >> 3;                  // node within wave (0..7)
    int n = (blockIdx.x >> 3) * 32 + wave * 8 + nsub;
    bool nvalid = (n < Nn);
    int nc = nvalid ? n : (Nn - 1);

    int h = slice >> 1;
    const char* Hs = (const char*)(Hc + (size_t)slice * (NPAD * 32));
    const float* aS = a_srcP + (size_t)h * Nn;

    int beg = rowptr[nc];
    int deg = rowptr[nc + 1] - beg;
    if (!nvalid) deg = 0;
    float adst = a_dstP[(size_t)h * Nn + nc];

    // wave-uniform trip count = max degree over the 8 nodes (c8 lanes identical)
    int md = deg;
    #pragma unroll
    for (int d = 8; d <= 32; d <<= 1) md = max(md, __shfl_xor(md, d));

    float ssum = 0.f;
    float4 acc = make_float4(0.f, 0.f, 0.f, 0.f);

    int s_cur = 0;
    if (deg > 0) s_cur = csr_src[beg];
    for (int i = 0; i < md; ++i) {
        int s_nxt = 0;
        if (i + 1 < deg) s_nxt = csr_src[beg + i + 1];   // prefetch breaks load chain
        bool act = (i < deg);
        int s = act ? s_cur : 0;                         // row 0: harmless hot line
        float e = aS[s] + adst;
        e = fmaxf(e, SLOPE * e);                         // leaky relu (slope<1)
        float ex = act ? __expf(e) : 0.f;
        ssum += ex;
        ushort4 u = *(const ushort4*)(Hs + (size_t)s * 64 + c8 * 8);
        acc.x += ex * h2f(u.x);
        acc.y += ex * h2f(u.y);
        acc.z += ex * h2f(u.z);
        acc.w += ex * h2f(u.w);
        s_cur = s_nxt;
    }

    // self-loop + epilogue (all lane-private)
    float es = aS[nc] + adst;
    es = fmaxf(es, SLOPE * es);
    float exs = __expf(es);
    ushort4 us = *(const ushort4*)(Hs + (size_t)nc * 64 + c8 * 8);
    float rden = 1.f / (ssum + exs + 1e-16f);
    int ch = slice * 32 + c8 * 4;
    float4 b = *(const float4*)&bias[ch];
    float4 o4;
    o4.x = fmaxf((acc.x + exs * h2f(us.x)) * rden + b.x, 0.f);
    o4.y = fmaxf((acc.y + exs * h2f(us.y)) * rden + b.y, 0.f);
    o4.z = fmaxf((acc.z + exs * h2f(us.z)) * rden + b.z, 0.f);
    o4.w = fmaxf((acc.w + exs * h2f(us.w)) * rden + b.w, 0.f);

    if (nvalid) {
        if (out_f32) {
            *(float4*)&out_f32[(size_t)n * HC + ch] = o4;
        }
        if (out_h16c) {
            size_t idx = (size_t)slice * (NPAD * 32) + (size_t)n * 32 + c8 * 4;
            *(ushort4*)&out_h16c[idx] = make_ushort4(f2h(o4.x), f2h(o4.y), f2h(o4.z), f2h(o4.w));
        }
    }
}

// ---------------- launch ----------------

extern "C" void kernel_launch(void* const* d_in, const int* in_sizes, int n_in,
                              void* d_out, int out_size, void* d_ws, size_t ws_size,
                              hipStream_t stream) {
    const float* x0   = (const float*)d_in[0];
    const int*   eidx = (const int*)d_in[1];
    int Nn = in_sizes[0] / IN0;     // 50000
    int E  = in_sizes[1] / 2;       // 850000
    int E_rand = E - Nn;            // 800000 random edges; self-loops inline
    const int* srcp = eidx;
    const int* dstp = eidx + E;

    const float* Wl[3]    = {(const float*)d_in[2],  (const float*)d_in[6],  (const float*)d_in[10]};
    const float* attS[3]  = {(const float*)d_in[3],  (const float*)d_in[7],  (const float*)d_in[11]};
    const float* attD[3]  = {(const float*)d_in[4],  (const float*)d_in[8],  (const float*)d_in[12]};
    const float* biasl[3] = {(const float*)d_in[5],  (const float*)d_in[9],  (const float*)d_in[13]};
    int Kdims[3] = {IN0, HC, HC};

    // workspace carve
    char* p = (char*)d_ws;
    ushort* h16    = (ushort*)p; p += (size_t)NPAD * HC * sizeof(ushort);   // chunked [8][NPAD][32]
    ushort* Xc     = (ushort*)p; p += (size_t)NPAD * HC * sizeof(ushort);   // chunked
    float*  a_src_v= (float*)p;  p += (size_t)Nn * HEADS * sizeof(float);   // [H][Nn] planes
    float*  a_dst_v= (float*)p;  p += (size_t)Nn * HEADS * sizeof(float);   // [H][Nn] planes
    int*    rowptr = (int*)p;    p += (size_t)(Nn + 1) * sizeof(int);
    int*    deg    = (int*)p;    p += (size_t)Nn * sizeof(int);
    int*    cur    = (int*)p;    p += (size_t)Nn * sizeof(int);
    int*    csr_src= (int*)p;    p += (size_t)E_rand * sizeof(int);
    ushort* Wc[3];
    for (int l = 0; l < 3; l++) {
        Wc[l] = (ushort*)p; p += (size_t)HC * Kdims[l] * sizeof(ushort);
    }

    int NB = (Nn + 1023) / 1024;
    int B0 = (E_rand + 255) / 256;
    int B1 = (Nn * IN0 + 255) / 256;
    int Bprep = B0 + B1 + 128 + 256 + 256;

    hipMemsetAsync(deg, 0, (size_t)Nn * sizeof(int), stream);
    k_prep<<<Bprep, 256, 0, stream>>>(dstp, E_rand, deg,
                                      x0, Xc, Nn * IN0,
                                      Wl[0], Wc[0], Wl[1], Wc[1], Wl[2], Wc[2],
                                      B0, B1);
    k_scan<<<NB, 1024, 0, stream>>>(deg, Nn, rowptr, cur);
    k_scatter<<<(E_rand + 255) / 256, 256, 0, stream>>>(srcp, dstp, E_rand, cur, csr_src);

    dim3 g(784);                 // 49 groups x (8 row-blocks x 2 col-blocks), XCD-swizzled
    dim3 ga(8 * ((Nn + 31) / 32)); // (slice x node-group); slice = bid%8 -> XCD affinity
    for (int l = 0; l < 3; l++) {
        if (l == 0)
            k_gemm_att<128><<<g, 256, 0, stream>>>(Xc, Wc[l], attS[l], attD[l],
                                                   h16, a_src_v, a_dst_v, Nn);
        else
            k_gemm_att<256><<<g, 256, 0, stream>>>(Xc, Wc[l], attS[l], attD[l],
                                                   h16, a_src_v, a_dst_v, Nn);
        if (l < 2) {
            k_aggregate<<<ga, 256, 0, stream>>>(h16, a_src_v, a_dst_v, rowptr, csr_src,
                                                biasl[l], nullptr, Xc, Nn);
        } else {
            k_aggregate<<<ga, 256, 0, stream>>>(h16, a_src_v, a_dst_v, rowptr, csr_src,
                                                biasl[l], (float*)d_out, nullptr, Nn);
        }
    }
}

// Round 3
// 471.429 us; speedup vs baseline: 1.3440x; 1.0968x over previous
//
#include <hip/hip_runtime.h>
#include <hip/hip_fp16.h>
#include <math.h>

#define IN0    128
#define HEADS  4
#define CDIM   64
#define HC     256
#define SLOPE  0.2f
#define NPAD   50176   // 392*128, row padding
#define BK     32      // k-chunk (halves) = 64 B

typedef __attribute__((ext_vector_type(8))) _Float16 f16x8;
typedef __attribute__((ext_vector_type(4))) float f32x4;

__device__ __forceinline__ float h2f(ushort u) {
    __half h = *(const __half*)&u;
    return __half2float(h);
}
__device__ __forceinline__ ushort f2h(float f) {
    __half h = __float2half_rn(f);
    return *(ushort*)&h;
}

// ---------------- fused prep: degree + xconv(fp16,chunked) + wconv(fp16,chunked) x3 ----------------

__device__ __forceinline__ void wconv_body(const float* __restrict__ W,
                                           ushort* __restrict__ Wc, int K, int b) {
    int tid = b * 256 + threadIdx.x;     // K*256 threads
    int n = tid & 255;                   // output col (coalesced read)
    int k = tid >> 8;
    if (k >= K) return;
    Wc[(size_t)(k >> 5) * (HC * BK) + n * BK + (k & 31)] = f2h(W[(size_t)k * HC + n]);
}

__global__ __launch_bounds__(256) void k_prep(
        const int* __restrict__ dst_rand, int E_rand, int* __restrict__ deg,
        const float* __restrict__ x0, ushort* __restrict__ Xc, int totalx,
        const float* __restrict__ W0, ushort* __restrict__ Wc0,
        const float* __restrict__ W1, ushort* __restrict__ Wc1,
        const float* __restrict__ W2, ushort* __restrict__ Wc2,
        int B0, int B1) {
    int b = blockIdx.x;
    if (b < B0) {
        int i = b * 256 + threadIdx.x;
        if (i < E_rand) atomicAdd(&deg[dst_rand[i]], 1);
        return;
    }
    b -= B0;
    if (b < B1) {                        // xconv: x0 [N][128] -> Xc [4][NPAD][32]
        int i = b * 256 + threadIdx.x;
        if (i < totalx) {
            int n = i >> 7, k = i & 127;
            Xc[(size_t)(k >> 5) * (NPAD * BK) + n * BK + (k & 31)] = f2h(x0[i]);
        }
        return;
    }
    b -= B1;
    if (b < 128) { wconv_body(W0, Wc0, 128, b); return; }
    b -= 128;
    if (b < 256) { wconv_body(W1, Wc1, 256, b); return; }
    b -= 256;
    wconv_body(W2, Wc2, 256, b);
}

// ---------------- single-kernel scan (prefix-of-prefixes brute force) + degree hist ----------------

__global__ __launch_bounds__(1024) void k_scan(const int* __restrict__ deg, int Nn,
                                               int* __restrict__ rowptr,
                                               int* __restrict__ cur,
                                               int* __restrict__ ghist) {
    __shared__ int smem[1024];
    __shared__ int lhist[64];
    int tid = threadIdx.x;
    if (tid < 64) lhist[tid] = 0;
    int pre = 0;
    int limit = blockIdx.x * 1024;
    for (int i = tid; i < limit; i += 1024) pre += deg[i];
    smem[tid] = pre;
    __syncthreads();
    #pragma unroll
    for (int d = 512; d >= 1; d >>= 1) {
        if (tid < d) smem[tid] += smem[tid + d];
        __syncthreads();
    }
    int s_off = smem[0];
    __syncthreads();
    int i = blockIdx.x * 1024 + tid;
    int v = (i < Nn) ? deg[i] : 0;
    if (i < Nn) atomicAdd(&lhist[min(v, 63)], 1);
    smem[tid] = v;
    __syncthreads();
    #pragma unroll
    for (int d = 1; d < 1024; d <<= 1) {
        int t = 0;
        if (tid >= d) t = smem[tid - d];
        __syncthreads();
        smem[tid] += t;
        __syncthreads();
    }
    if (i < Nn) {
        int e = s_off + smem[tid] - v;
        rowptr[i] = e;
        cur[i] = e;
    }
    if (blockIdx.x == gridDim.x - 1 && tid == 1023) rowptr[Nn] = s_off + smem[1023];
    if (tid < 64) {
        int c = lhist[tid];
        if (c) atomicAdd(&ghist[tid], c);
    }
}

// 1-wave exclusive scan of the 64 degree bins
__global__ __launch_bounds__(64) void k_binscan(const int* __restrict__ ghist,
                                                int* __restrict__ bincur) {
    int t = threadIdx.x;
    int v = ghist[t];
    int x = v;
    #pragma unroll
    for (int d = 1; d < 64; d <<= 1) {
        int y = __shfl_up(x, d);
        if (t >= d) x += y;
    }
    bincur[t] = x - v;   // exclusive prefix
}

// counting-sort nodes by degree: order[pos] = n, begdeg[pos] = (rowptr[n], deg[n]).
// LDS-aggregated so global atomics are 64/block.
__global__ __launch_bounds__(1024) void k_order(const int* __restrict__ deg,
                                                const int* __restrict__ rowptr, int Nn,
                                                int* __restrict__ bincur,
                                                int* __restrict__ order,
                                                int2* __restrict__ begdeg) {
    __shared__ int lh[64], lbase[64];
    int tid = threadIdx.x;
    if (tid < 64) lh[tid] = 0;
    __syncthreads();
    int n = blockIdx.x * 1024 + tid;
    int b = 0, r = 0, dg = 0;
    if (n < Nn) {
        dg = deg[n];
        b = min(dg, 63);
        r = atomicAdd(&lh[b], 1);
    }
    __syncthreads();
    if (tid < 64) {
        int c = lh[tid];
        lbase[tid] = c ? atomicAdd(&bincur[tid], c) : 0;
    }
    __syncthreads();
    if (n < Nn) {
        int pos = lbase[b] + r;
        order[pos] = n;
        begdeg[pos] = make_int2(rowptr[n], dg);
    }
}

__global__ void k_scatter(const int* __restrict__ src, const int* __restrict__ dst, int E_rand,
                          int* __restrict__ cur, int* __restrict__ csr_src) {
    int i = blockIdx.x * blockDim.x + threadIdx.x;
    if (i < E_rand) {
        int d = dst[i];
        int p = atomicAdd(&cur[d], 1);
        csr_src[p] = src[i];
    }
}

// ---------------- fused GEMM + attention scores (fp16 MFMA, no LDS, chunked operands) ----------------
// H output is stored CHUNKED [HC/32][NPAD][32] so the aggregate can slice it per-XCD.
// a_src/a_dst are stored as per-head planes [HEADS][M] for per-XCD L2 residency.

template<int K>
__global__ __launch_bounds__(256) void k_gemm_att(const ushort* __restrict__ Xc,
                                                  const ushort* __restrict__ Wc,
                                                  const float* __restrict__ attS,
                                                  const float* __restrict__ attD,
                                                  ushort* __restrict__ H16out,
                                                  float* __restrict__ a_src_v,
                                                  float* __restrict__ a_dst_v,
                                                  int M) {
    int id    = blockIdx.x;
    int group = id >> 4;
    int sub   = id & 15;
    int row0  = (group * 8 + (sub & 7)) * 128;
    int colb  = sub >> 3;
    int col0  = colb * 128;

    int t    = threadIdx.x;
    int wave = t >> 6, lane = t & 63;
    int wm = wave & 1, wn = wave >> 1;
    int quad = lane >> 4, l16 = lane & 15;

    f32x4 acc[4][4];
    #pragma unroll
    for (int i = 0; i < 4; i++)
        #pragma unroll
        for (int j = 0; j < 4; j++) acc[i][j] = (f32x4){0.f, 0.f, 0.f, 0.f};

    constexpr int NK = K / BK;
    #pragma unroll
    for (int kc = 0; kc < NK; kc++) {
        f16x8 a[4], b[4];
        #pragma unroll
        for (int mt = 0; mt < 4; mt++) {
            size_t ga = (size_t)kc * (NPAD * BK)
                      + (size_t)(row0 + wm * 64 + mt * 16 + l16) * BK + quad * 8;
            a[mt] = *(const f16x8*)&Xc[ga];
        }
        #pragma unroll
        for (int nt = 0; nt < 4; nt++) {
            size_t gb = (size_t)kc * (HC * BK)
                      + (size_t)(col0 + wn * 64 + nt * 16 + l16) * BK + quad * 8;
            b[nt] = *(const f16x8*)&Wc[gb];
        }
        #pragma unroll
        for (int mt = 0; mt < 4; mt++)
            #pragma unroll
            for (int nt = 0; nt < 4; nt++)
                acc[mt][nt] = __builtin_amdgcn_mfma_f32_16x16x32_f16(a[mt], b[nt], acc[mt][nt], 0, 0, 0);
    }

    // epilogue 1: store H as fp16 CHUNKED (C/D layout col=lane&15, row=quad*4+reg)
    #pragma unroll
    for (int mt = 0; mt < 4; mt++) {
        #pragma unroll
        for (int r = 0; r < 4; r++) {
            int row = row0 + wm*64 + mt*16 + quad*4 + r;
            if (row >= M) continue;
            #pragma unroll
            for (int nt = 0; nt < 4; nt++) {
                int col = col0 + wn*64 + nt*16 + l16;
                size_t idx = (size_t)(col >> 5) * (NPAD * 32) + (size_t)row * 32 + (col & 31);
                H16out[idx] = f2h(acc[mt][nt][r]);
            }
        }
    }

    // epilogue 2: att score dots; this wave's cols = head (2*colb + wn).
    int headw = colb * 2 + wn;
    float sS[4], sD[4];
    #pragma unroll
    for (int nt = 0; nt < 4; nt++) {
        sS[nt] = attS[headw * CDIM + nt*16 + l16];
        sD[nt] = attD[headw * CDIM + nt*16 + l16];
    }
    #pragma unroll
    for (int mt = 0; mt < 4; mt++) {
        #pragma unroll
        for (int r = 0; r < 4; r++) {
            float ps = 0.f, pd = 0.f;
            #pragma unroll
            for (int nt = 0; nt < 4; nt++) {
                float av = acc[mt][nt][r];
                ps += av * sS[nt];
                pd += av * sD[nt];
            }
            #pragma unroll
            for (int d = 1; d <= 8; d <<= 1) {
                ps += __shfl_xor(ps, d);
                pd += __shfl_xor(pd, d);
            }
            int row = row0 + wm*64 + mt*16 + quad*4 + r;
            if (l16 == 0 && row < M) {
                a_src_v[(size_t)headw * M + row] = ps;
                a_dst_v[(size_t)headw * M + row] = pd;
            }
        }
    }
}

// ---------------- aggregation: XCD-sliced, degree-grouped, batch-4 pipelined ----------------
// slice = blockIdx%8 -> XCD affinity: each XCD's L2 holds its 3.2 MB H-slice +
// 200 KB score plane (proven: FETCH 210->62 MB). Lane = node_sub(3b) x ch-quad(3b);
// ssum/acc fully lane-private, zero shuffles in loop.
// r2 fix 1: nodes assigned via degree-sorted order[] -> wave-max(deg) ~ mean(deg),
//   cutting ~35% padded iterations.
// r2 fix 2: batch-4 edge pipeline -- 4 H-gathers + 4 aS-gathers issued up front,
//   next-batch csr indices prefetched, then compute: per-iter issue work (~200cy)
//   covers L2 gather latency with ~2 waves instead of ~8.

__device__ __forceinline__ void edge_acc(bool act, float aval, float adst,
                                         ushort4 u, float& ssum, float4& acc) {
    float e = aval + adst;
    e = fmaxf(e, SLOPE * e);
    float ex = act ? __expf(e) : 0.f;
    ssum += ex;
    acc.x += ex * h2f(u.x);
    acc.y += ex * h2f(u.y);
    acc.z += ex * h2f(u.z);
    acc.w += ex * h2f(u.w);
}

__global__ __launch_bounds__(256) void k_aggregate(
        const ushort* __restrict__ Hc,      // chunked fp16 [8][NPAD][32]
        const float* __restrict__ a_srcP,   // [HEADS][Nn]
        const float* __restrict__ a_dstP,   // [HEADS][Nn]
        const int* __restrict__ order,      // degree-sorted node ids
        const int2* __restrict__ begdeg,    // (rowptr[n], deg[n]) in order[] layout
        const int* __restrict__ csr_src,
        const float* __restrict__ bias,
        float* __restrict__ out_f32,        // nullable
        ushort* __restrict__ out_h16c,      // nullable (fp16, CHUNKED)
        int Nn) {
    int lane  = threadIdx.x & 63;
    int wave  = threadIdx.x >> 6;
    int slice = blockIdx.x & 7;             // == XCD under round-robin dispatch
    int c8    = lane & 7;                   // channel quad: ch = slice*32 + c8*4
    int nsub  = lane >> 3;                  // node within wave (0..7)
    int posidx = (blockIdx.x >> 3) * 32 + wave * 8 + nsub;
    bool nvalid = (posidx < Nn);
    int pi = nvalid ? posidx : (Nn - 1);

    int h = slice >> 1;
    const char* Hs = (const char*)(Hc + (size_t)slice * (NPAD * 32));
    const float* aS = a_srcP + (size_t)h * Nn;

    int n = order[pi];
    int2 bd = begdeg[pi];
    int beg = bd.x;
    int deg = nvalid ? bd.y : 0;
    float adst = a_dstP[(size_t)h * Nn + n];

    // wave-uniform trip count = max degree over the 8 nodes (degree-similar now)
    int md = deg;
    #pragma unroll
    for (int d = 8; d <= 32; d <<= 1) md = max(md, __shfl_xor(md, d));

    float ssum = 0.f;
    float4 acc = make_float4(0.f, 0.f, 0.f, 0.f);

    int s0 = 0, s1 = 0, s2 = 0, s3 = 0;
    if (0 < deg) s0 = csr_src[beg + 0];
    if (1 < deg) s1 = csr_src[beg + 1];
    if (2 < deg) s2 = csr_src[beg + 2];
    if (3 < deg) s3 = csr_src[beg + 3];

    for (int base = 0; base < md; base += 4) {
        // issue all gathers for the current batch first (MLP)
        ushort4 u0 = *(const ushort4*)(Hs + (size_t)s0 * 64 + c8 * 8);
        ushort4 u1 = *(const ushort4*)(Hs + (size_t)s1 * 64 + c8 * 8);
        ushort4 u2 = *(const ushort4*)(Hs + (size_t)s2 * 64 + c8 * 8);
        ushort4 u3 = *(const ushort4*)(Hs + (size_t)s3 * 64 + c8 * 8);
        float a0 = aS[s0], a1 = aS[s1], a2 = aS[s2], a3 = aS[s3];
        // prefetch next batch's source indices (L1-hot sequential)
        int t0 = 0, t1 = 0, t2 = 0, t3 = 0;
        int nb = base + 4;
        if (nb + 0 < deg) t0 = csr_src[beg + nb + 0];
        if (nb + 1 < deg) t1 = csr_src[beg + nb + 1];
        if (nb + 2 < deg) t2 = csr_src[beg + nb + 2];
        if (nb + 3 < deg) t3 = csr_src[beg + nb + 3];
        // consume
        edge_acc(base + 0 < deg, a0, adst, u0, ssum, acc);
        edge_acc(base + 1 < deg, a1, adst, u1, ssum, acc);
        edge_acc(base + 2 < deg, a2, adst, u2, ssum, acc);
        edge_acc(base + 3 < deg, a3, adst, u3, ssum, acc);
        s0 = t0; s1 = t1; s2 = t2; s3 = t3;
    }

    // self-loop + epilogue (all lane-private)
    float es = aS[n] + adst;
    es = fmaxf(es, SLOPE * es);
    float exs = __expf(es);
    ushort4 us = *(const ushort4*)(Hs + (size_t)n * 64 + c8 * 8);
    float rden = 1.f / (ssum + exs + 1e-16f);
    int ch = slice * 32 + c8 * 4;
    float4 b = *(const float4*)&bias[ch];
    float4 o4;
    o4.x = fmaxf((acc.x + exs * h2f(us.x)) * rden + b.x, 0.f);
    o4.y = fmaxf((acc.y + exs * h2f(us.y)) * rden + b.y, 0.f);
    o4.z = fmaxf((acc.z + exs * h2f(us.z)) * rden + b.z, 0.f);
    o4.w = fmaxf((acc.w + exs * h2f(us.w)) * rden + b.w, 0.f);

    if (nvalid) {
        if (out_f32) {
            *(float4*)&out_f32[(size_t)n * HC + ch] = o4;   // 8 c8-lanes cover 128B/node
        }
        if (out_h16c) {
            size_t idx = (size_t)slice * (NPAD * 32) + (size_t)n * 32 + c8 * 4;
            *(ushort4*)&out_h16c[idx] = make_ushort4(f2h(o4.x), f2h(o4.y), f2h(o4.z), f2h(o4.w));
        }
    }
}

// ---------------- launch ----------------

extern "C" void kernel_launch(void* const* d_in, const int* in_sizes, int n_in,
                              void* d_out, int out_size, void* d_ws, size_t ws_size,
                              hipStream_t stream) {
    const float* x0   = (const float*)d_in[0];
    const int*   eidx = (const int*)d_in[1];
    int Nn = in_sizes[0] / IN0;     // 50000
    int E  = in_sizes[1] / 2;       // 850000
    int E_rand = E - Nn;            // 800000 random edges; self-loops inline
    const int* srcp = eidx;
    const int* dstp = eidx + E;

    const float* Wl[3]    = {(const float*)d_in[2],  (const float*)d_in[6],  (const float*)d_in[10]};
    const float* attS[3]  = {(const float*)d_in[3],  (const float*)d_in[7],  (const float*)d_in[11]};
    const float* attD[3]  = {(const float*)d_in[4],  (const float*)d_in[8],  (const float*)d_in[12]};
    const float* biasl[3] = {(const float*)d_in[5],  (const float*)d_in[9],  (const float*)d_in[13]};
    int Kdims[3] = {IN0, HC, HC};

    // workspace carve
    char* p = (char*)d_ws;
    ushort* h16    = (ushort*)p; p += (size_t)NPAD * HC * sizeof(ushort);   // chunked [8][NPAD][32]
    ushort* Xc     = (ushort*)p; p += (size_t)NPAD * HC * sizeof(ushort);   // chunked
    float*  a_src_v= (float*)p;  p += (size_t)Nn * HEADS * sizeof(float);   // [H][Nn] planes
    float*  a_dst_v= (float*)p;  p += (size_t)Nn * HEADS * sizeof(float);   // [H][Nn] planes
    int*    rowptr = (int*)p;    p += (size_t)(Nn + 1) * sizeof(int);
    int*    deg    = (int*)p;    p += (size_t)Nn * sizeof(int);
    int*    cur    = (int*)p;    p += (size_t)Nn * sizeof(int);
    int*    csr_src= (int*)p;    p += (size_t)E_rand * sizeof(int);
    int*    ghist  = (int*)p;    p += 64 * sizeof(int);
    int*    bincur = (int*)p;    p += 64 * sizeof(int);
    int*    order  = (int*)p;    p += (size_t)Nn * sizeof(int);
    int2*   begdeg = (int2*)p;   p += (size_t)Nn * sizeof(int2);
    ushort* Wc[3];
    for (int l = 0; l < 3; l++) {
        Wc[l] = (ushort*)p; p += (size_t)HC * Kdims[l] * sizeof(ushort);
    }

    int NB = (Nn + 1023) / 1024;
    int B0 = (E_rand + 255) / 256;
    int B1 = (Nn * IN0 + 255) / 256;
    int Bprep = B0 + B1 + 128 + 256 + 256;

    hipMemsetAsync(deg, 0, (size_t)Nn * sizeof(int), stream);
    hipMemsetAsync(ghist, 0, 64 * sizeof(int), stream);
    k_prep<<<Bprep, 256, 0, stream>>>(dstp, E_rand, deg,
                                      x0, Xc, Nn * IN0,
                                      Wl[0], Wc[0], Wl[1], Wc[1], Wl[2], Wc[2],
                                      B0, B1);
    k_scan<<<NB, 1024, 0, stream>>>(deg, Nn, rowptr, cur, ghist);
    k_binscan<<<1, 64, 0, stream>>>(ghist, bincur);
    k_scatter<<<(E_rand + 255) / 256, 256, 0, stream>>>(srcp, dstp, E_rand, cur, csr_src);
    k_order<<<NB, 1024, 0, stream>>>(deg, rowptr, Nn, bincur, order, begdeg);

    dim3 g(784);                 // 49 groups x (8 row-blocks x 2 col-blocks), XCD-swizzled
    dim3 ga(8 * ((Nn + 31) / 32)); // (slice x node-group); slice = bid%8 -> XCD affinity
    for (int l = 0; l < 3; l++) {
        if (l == 0)
            k_gemm_att<128><<<g, 256, 0, stream>>>(Xc, Wc[l], attS[l], attD[l],
                                                   h16, a_src_v, a_dst_v, Nn);
        else
            k_gemm_att<256><<<g, 256, 0, stream>>>(Xc, Wc[l], attS[l], attD[l],
                                                   h16, a_src_v, a_dst_v, Nn);
        if (l < 2) {
            k_aggregate<<<ga, 256, 0, stream>>>(h16, a_src_v, a_dst_v, order, begdeg, csr_src,
                                                biasl[l], nullptr, Xc, Nn);
        } else {
            k_aggregate<<<ga, 256, 0, stream>>>(h16, a_src_v, a_dst_v, order, begdeg, csr_src,
                                                biasl[l], (float*)d_out, nullptr, Nn);
        }
    }
}